// Round 6
// baseline (127.999 us; speedup 1.0000x reference)
//
#include <hip/hip_runtime.h>
#include <hip/hip_bf16.h>

// Problem constants (M=41 in the reference)
#define M41   41
#define HALF  20
#define NPAIR 1261            // #(m,n) with |m|,|n|<=20 and |m+n|<=20
#define NTRIP (NPAIR * M41)   // 51701 triplets

static __device__ __forceinline__ unsigned short f2bf(float f) {
    __hip_bfloat16 h = __float2bfloat16(f);   // round-to-nearest-even
    return *reinterpret_cast<unsigned short*>(&h);
}

// Output: complex (B, 2, 2T) C-order, re/im interleaved -> ushort4 per (b,c,t):
// [f1.re, f1.im, f2.re, f2.im] at ushort4 index (b*2+c)*T + t.
__global__ __launch_bounds__(256) void so_features(
    const float* __restrict__ E_real, const float* __restrict__ E_imag,
    ushort4* __restrict__ out)
{
    __shared__ float2 sE[M41][2];   // E[b, idx, c] as (re, im)
    __shared__ float  sT1[M41];     // term1 per k-index
    __shared__ float2 sT2[M41];     // term2 per k-index

    const int b   = blockIdx.y;
    const int tid = threadIdx.x;

    // Stage E[b] (41*2 complex fp32 = 656 B) into LDS
    if (tid < 2 * M41) {
        int base = b * (2 * M41) + tid;   // flat layout: b*82 + mi*2 + c
        sE[tid >> 1][tid & 1] = make_float2(E_real[base], E_imag[base]);
    }
    __syncthreads();

    // term1[kk] = |E[kk,0]|^2 + |E[kk,1]|^2
    // term2[kk] = E[kk,0]*E[40-kk,0] + E[kk,1]*E[40-kk,1]   (no conj)
    if (tid < M41) {
        float2 e0 = sE[tid][0], e1 = sE[tid][1];
        sT1[tid] = e0.x*e0.x + e0.y*e0.y + e1.x*e1.x + e1.y*e1.y;
        float2 g0 = sE[40 - tid][0], g1 = sE[40 - tid][1];
        sT2[tid] = make_float2(
            e0.x*g0.x - e0.y*g0.y + e1.x*g1.x - e1.y*g1.y,
            e0.x*g0.y + e0.y*g0.x + e1.x*g1.y + e1.y*g1.x);
    }
    __syncthreads();

    int t = blockIdx.x * 256 + tid;
    if (t >= NTRIP) return;

    int q  = t / M41;          // pair index 0..1260 (constant-div -> magic mul)
    int kk = t - q * M41;      // k + 20

    // Closed-form inversion of the Python (m,n) enumeration order.
    // First 651 pairs: mi=0..20, cumulative C(mi) = mi*(mi+41)/2.
    // Second half by symmetry (m,n)->(-m,-n) <=> q -> 1260-q.
    // Provably correct for all q: integer while-loops fix any sqrt seed error.
    int qq = q;
    bool flip = false;
    if (qq >= 651) { qq = 1260 - qq; flip = true; }
    float x = sqrtf(1681.0f + 8.0f * (float)qq);
    int mi = (int)((x - 41.0f) * 0.5f);
    if (mi < 0) mi = 0;
    while (((mi + 1) * (mi + 42)) / 2 <= qq) ++mi;   // C(mi+1) <= qq -> advance
    while ((mi * (mi + 41)) / 2 > qq)       --mi;    // C(mi)  > qq -> retreat
    int off = qq - (mi * (mi + 41)) / 2;
    int ni  = off + (HALF - mi);                     // n_min+20 = 20-mi for mi<=20
    if (flip) { mi = 40 - mi; ni = 40 - ni; }
    int mni = mi + ni - HALF;                        // (m+n)+20, in [0,40]

    float  t1 = sT1[kk];
    float2 t2 = sT2[kk];

    #pragma unroll
    for (int c = 0; c < 2; ++c) {
        float2 a  = sE[mi][c];
        float2 bb = sE[ni][c];
        float2 d  = sE[mni][c];
        // E1 = a*bb*conj(d)
        float2 ab = make_float2(a.x*bb.x - a.y*bb.y, a.x*bb.y + a.y*bb.x);
        float2 E1 = make_float2(ab.x*d.x + ab.y*d.y, ab.y*d.x - ab.x*d.y);
        ushort4 v;
        // feat1 = E1 * term1 (real scale)
        v.x = f2bf(E1.x * t1);
        v.y = f2bf(E1.y * t1);
        // feat2 = conj(E1) * term2
        v.z = f2bf(E1.x*t2.x + E1.y*t2.y);
        v.w = f2bf(E1.x*t2.y - E1.y*t2.x);
        out[(size_t)(b * 2 + c) * NTRIP + t] = v;
    }
}

extern "C" void kernel_launch(void* const* d_in, const int* in_sizes, int n_in,
                              void* d_out, int out_size, void* d_ws, size_t ws_size,
                              hipStream_t stream) {
    // R5 evidence: interleaved layout with d_in[0]->real gives a uniform
    // re/im swap signature (absmax ~ sqrt(2)*max|ref|).  Inputs appear to be
    // delivered in alphabetical key order: d_in[0] = E_imag, d_in[1] = E_real.
    // (The equivalent "[im,re] per complex" convention is fixed by the same
    // swap: out -> i*conj(out).)
    const float* E_imag = (const float*)d_in[0];
    const float* E_real = (const float*)d_in[1];
    ushort4* out = (ushort4*)d_out;

    int B = in_sizes[0] / (2 * M41);   // 128 for the bench shapes

    dim3 grid((NTRIP + 255) / 256, B);
    so_features<<<grid, 256, 0, stream>>>(E_real, E_imag, out);
}

// Round 7
// 121.403 us; speedup vs baseline: 1.0543x; 1.0543x over previous
//
#include <hip/hip_runtime.h>
#include <hip/hip_bf16.h>

// Problem constants (M=41 in the reference)
#define M41   41
#define HALF  20
#define NPAIR 1261            // #(m,n) with |m|,|n|<=20 and |m+n|<=20
#define NTRIP (NPAIR * M41)   // 51701 triplets
#define NPAIRS2 25850         // floor(NTRIP/2) full 2-t pairs per plane

static __device__ __forceinline__ unsigned short f2bf(float f) {
    __hip_bfloat16 h = __float2bfloat16(f);   // round-to-nearest-even
    return *reinterpret_cast<unsigned short*>(&h);
}
static __device__ __forceinline__ unsigned int pk2(float lo, float hi) {
    return (unsigned int)f2bf(lo) | ((unsigned int)f2bf(hi) << 16);
}

// q -> packed (mi | ni<<8 | mni<<16).  Closed-form inversion of the Python
// (m,n) enumeration; integer while-loops make it exact for all q.
static __device__ __forceinline__ int pair_decode(int q) {
    int qq = q; bool flip = false;
    if (qq >= 651) { qq = 1260 - qq; flip = true; }
    float x = sqrtf(1681.0f + 8.0f * (float)qq);
    int mi = (int)((x - 41.0f) * 0.5f);
    if (mi < 0) mi = 0;
    while (((mi + 1) * (mi + 42)) / 2 <= qq) ++mi;
    while ((mi * (mi + 41)) / 2 > qq)       --mi;
    int off = qq - (mi * (mi + 41)) / 2;
    int ni  = off + (HALF - mi);
    if (flip) { mi = 40 - mi; ni = 40 - ni; }
    int mni = mi + ni - HALF;
    return mi | (ni << 8) | (mni << 16);
}

static __device__ __forceinline__ float2 e1_of(const float2 (*sE)[2], int d, int c) {
    float2 a  = sE[d & 255][c];
    float2 bb = sE[(d >> 8) & 255][c];
    float2 dd = sE[(d >> 16) & 255][c];
    float2 ab = make_float2(a.x*bb.x - a.y*bb.y, a.x*bb.y + a.y*bb.x);
    return make_float2(ab.x*dd.x + ab.y*dd.y, ab.y*dd.x - ab.x*dd.y);  // a*bb*conj(dd)
}

// feat1 = E1*t1 (real scale), feat2 = conj(E1)*t2 -> packed bf16 complex pair
static __device__ __forceinline__ uint2 feat(float2 E1, float t1, float2 t2) {
    uint2 r;
    r.x = pk2(E1.x * t1, E1.y * t1);
    r.y = pk2(E1.x*t2.x + E1.y*t2.y, E1.x*t2.y - E1.y*t2.x);
    return r;
}

// Output: complex (B, 2, 2T) C-order, re/im interleaved bf16.
// out viewed as uint (4 B = one bf16 complex); plane (b,c) = 2*NTRIP uints.
__global__ __launch_bounds__(256) void so_features(
    const float* __restrict__ E_real, const float* __restrict__ E_imag,
    unsigned int* __restrict__ out)
{
    __shared__ float2 sE[M41][2];
    __shared__ float  sT1[M41];
    __shared__ float2 sT2[M41];

    const int b   = blockIdx.y;
    const int tid = threadIdx.x;

    if (tid < 2 * M41) {
        int base = b * (2 * M41) + tid;
        sE[tid >> 1][tid & 1] = make_float2(E_real[base], E_imag[base]);
    }
    __syncthreads();

    if (tid < M41) {
        float2 e0 = sE[tid][0], e1 = sE[tid][1];
        sT1[tid] = e0.x*e0.x + e0.y*e0.y + e1.x*e1.x + e1.y*e1.y;
        float2 g0 = sE[40 - tid][0], g1 = sE[40 - tid][1];
        sT2[tid] = make_float2(
            e0.x*g0.x - e0.y*g0.y + e1.x*g1.x - e1.y*g1.y,
            e0.x*g0.y + e0.y*g0.x + e1.x*g1.y + e1.y*g1.x);
    }
    __syncthreads();

    int p = blockIdx.x * 256 + tid;
    if (p > NPAIRS2) return;

    size_t base0 = (size_t)(b * 2 + 0) * (2 * NTRIP);  // uint units
    size_t base1 = (size_t)(b * 2 + 1) * (2 * NTRIP);

    if (p == NPAIRS2) {
        // leftover solos: c=0 plane t=51700 (q=1260,kk=40); c=1 plane t=0 (q=0,kk=0)
        int dA = pair_decode(1260);
        uint2 vA = feat(e1_of(sE, dA, 0), sT1[40], sT2[40]);
        *(uint2*)&out[base0 + 2 * (size_t)(NTRIP - 1)] = vA;
        int dB = pair_decode(0);
        uint2 vB = feat(e1_of(sE, dB, 1), sT1[0], sT2[0]);
        *(uint2*)&out[base1] = vB;
        return;
    }

    int t0 = 2 * p;
    int q0 = t0 / M41;            // magic-mul div
    int k0 = t0 - q0 * M41;
    int q1 = q0, k1 = k0 + 1; if (k1 == M41) { k1 = 0; ++q1; }
    int q2 = q1, k2 = k1 + 1; if (k2 == M41) { k2 = 0; ++q2; }

    int d0 = pair_decode(q0);
    int dX = (q2 > q0) ? pair_decode(q0 + 1) : d0;   // at most one q step in a 3-window
    int s1 = (q1 > q0) ? dX : d0;
    int s2 = (q2 > q0) ? dX : d0;

    float  t1a = sT1[k0], t1b = sT1[k1], t1c = sT1[k2];
    float2 t2a = sT2[k0], t2b = sT2[k1], t2c = sT2[k2];

    // c = 0 plane: 16B-aligned pair (t0, t0+1)
    {
        float2 e0 = e1_of(sE, d0, 0);
        float2 e1v = (s1 == d0) ? e0 : e1_of(sE, s1, 0);
        uint2 fa = feat(e0,  t1a, t2a);
        uint2 fb = feat(e1v, t1b, t2b);
        uint4 v; v.x = fa.x; v.y = fa.y; v.z = fb.x; v.w = fb.y;
        *(uint4*)&out[base0 + 2 * (size_t)t0] = v;
    }
    // c = 1 plane: 16B-aligned pair (t0+1, t0+2)
    {
        float2 e1v = e1_of(sE, s1, 1);
        float2 e2v = (s2 == s1) ? e1v : e1_of(sE, s2, 1);
        uint2 fa = feat(e1v, t1b, t2b);
        uint2 fb = feat(e2v, t1c, t2c);
        uint4 v; v.x = fa.x; v.y = fa.y; v.z = fb.x; v.w = fb.y;
        *(uint4*)&out[base1 + 2 * (size_t)t0 + 2] = v;
    }
}

extern "C" void kernel_launch(void* const* d_in, const int* in_sizes, int n_in,
                              void* d_out, int out_size, void* d_ws, size_t ws_size,
                              hipStream_t stream) {
    // Verified R6: inputs arrive with d_in[0] = E_imag, d_in[1] = E_real.
    const float* E_imag = (const float*)d_in[0];
    const float* E_real = (const float*)d_in[1];
    unsigned int* out = (unsigned int*)d_out;

    int B = in_sizes[0] / (2 * M41);   // 128 for the bench shapes

    dim3 grid((NPAIRS2 + 1 + 255) / 256, B);   // 101 x B
    so_features<<<grid, 256, 0, stream>>>(E_real, E_imag, out);
}

// Round 8
// 117.905 us; speedup vs baseline: 1.0856x; 1.0297x over previous
//
#include <hip/hip_runtime.h>
#include <hip/hip_bf16.h>

// Problem constants (M=41 in the reference)
#define M41    41
#define HALF   20
#define NPAIR  1261            // #(m,n) with |m|,|n|<=20 and |m+n|<=20
#define NTRIP  (NPAIR * M41)   // 51701 triplets
#define NGRP   12925           // full 4-t groups per plane (t 0..51699 / 1..51700)
#define P_PER_B (NGRP + 1)     // + 1 solo thread
#define QSLOTS 28              // max distinct q per 1024-t block window (<=26) + slack

#if defined(__has_builtin)
# if __has_builtin(__builtin_amdgcn_cvt_pk_bf16_f32)
#  define HAVE_PK_BF16 1
# endif
#endif

static __device__ __forceinline__ unsigned short f2bf_sw(float f) {
    unsigned int u = __float_as_uint(f);
    unsigned int r = u + 0x7fffu + ((u >> 16) & 1u);   // RNE (finite inputs)
    return (unsigned short)(r >> 16);
}
static __device__ __forceinline__ unsigned int pk2(float lo, float hi) {
#ifdef HAVE_PK_BF16
    typedef __bf16 bf2 __attribute__((ext_vector_type(2)));
    union { bf2 v; unsigned int u; } cv;
    cv.v = __builtin_amdgcn_cvt_pk_bf16_f32(lo, hi);   // lo -> low half
    return cv.u;
#else
    return (unsigned int)f2bf_sw(lo) | ((unsigned int)f2bf_sw(hi) << 16);
#endif
}

// q -> packed (mi | ni<<8 | mni<<16).  Closed-form inversion of the Python
// (m,n) enumeration; integer while-loops make it exact for all q.
static __device__ __forceinline__ int pair_decode(int q) {
    int qq = q; bool flip = false;
    if (qq >= 651) { qq = 1260 - qq; flip = true; }
    float x = sqrtf(1681.0f + 8.0f * (float)qq);
    int mi = (int)((x - 41.0f) * 0.5f);
    if (mi < 0) mi = 0;
    while (((mi + 1) * (mi + 42)) / 2 <= qq) ++mi;
    while ((mi * (mi + 41)) / 2 > qq)       --mi;
    int off = qq - (mi * (mi + 41)) / 2;
    int ni  = off + (HALF - mi);
    if (flip) { mi = 40 - mi; ni = 40 - ni; }
    return mi | (ni << 8) | ((mi + ni - HALF) << 16);
}

static __device__ __forceinline__ float2 e1_of(const float2 (*sE)[2], int d, int c) {
    float2 a  = sE[d & 255][c];
    float2 bb = sE[(d >> 8) & 255][c];
    float2 dd = sE[(d >> 16) & 255][c];
    float2 ab = make_float2(a.x*bb.x - a.y*bb.y, a.x*bb.y + a.y*bb.x);
    return make_float2(ab.x*dd.x + ab.y*dd.y, ab.y*dd.x - ab.x*dd.y);  // a*bb*conj(dd)
}

// feat1 = E1*t1 (real), feat2 = conj(E1)*t2 -> two packed bf16 complex
static __device__ __forceinline__ uint2 feat(float2 E1, float t1, float2 t2) {
    uint2 r;
    r.x = pk2(E1.x * t1, E1.y * t1);
    r.y = pk2(E1.x*t2.x + E1.y*t2.y, E1.x*t2.y - E1.y*t2.x);
    return r;
}

// Output: complex (B, 2, 2T) C-order, re/im interleaved bf16.
// out viewed as uint (4 B = one bf16 complex); plane (b,c) = 2*NTRIP uints.
__global__ __launch_bounds__(256) void so_features(
    const float* __restrict__ E_real, const float* __restrict__ E_imag,
    unsigned int* __restrict__ out)
{
    __shared__ float2 sE[M41][2];
    __shared__ float  sT1[M41];
    __shared__ float2 sT2[M41];
    __shared__ float2 sE1[QSLOTS][2];   // E1(q, c) for the block's q-window

    const int b   = blockIdx.y;
    const int tid = threadIdx.x;
    const int q_lo = (1024 * blockIdx.x) / M41;

    if (tid < 2 * M41) {
        int base = b * (2 * M41) + tid;
        sE[tid >> 1][tid & 1] = make_float2(E_real[base], E_imag[base]);
    }
    __syncthreads();

    if (tid < M41) {
        float2 e0 = sE[tid][0], e1 = sE[tid][1];
        sT1[tid] = e0.x*e0.x + e0.y*e0.y + e1.x*e1.x + e1.y*e1.y;
        float2 g0 = sE[40 - tid][0], g1 = sE[40 - tid][1];
        sT2[tid] = make_float2(
            e0.x*g0.x - e0.y*g0.y + e1.x*g1.x - e1.y*g1.y,
            e0.x*g0.y + e0.y*g0.x + e1.x*g1.y + e1.y*g1.x);
    } else if (tid >= 64 && tid < 64 + QSLOTS) {
        int q = q_lo + (tid - 64);
        if (q <= NPAIR - 1) {
            int d = pair_decode(q);
            sE1[tid - 64][0] = e1_of(sE, d, 0);
            sE1[tid - 64][1] = e1_of(sE, d, 1);
        }
    }
    __syncthreads();

    int p = blockIdx.x * 256 + tid;
    if (p >= P_PER_B) return;

    const size_t base0 = (size_t)(b * 2 + 0) * (2 * NTRIP);  // uint units
    const size_t base1 = (size_t)(b * 2 + 1) * (2 * NTRIP);

    if (p == NGRP) {
        // solos: c=0 plane t=51700 (q=1260,kk=40); c=1 plane t=0 (q=0,kk=0)
        int dA = pair_decode(NPAIR - 1);
        uint2 vA = feat(e1_of(sE, dA, 0), sT1[40], sT2[40]);
        *(uint2*)&out[base0 + 2 * (size_t)(NTRIP - 1)] = vA;
        int dB = pair_decode(0);
        uint2 vB = feat(e1_of(sE, dB, 1), sT1[0], sT2[0]);
        *(uint2*)&out[base1] = vB;
        return;
    }

    int t0 = 4 * p;
    int q0 = t0 / M41;         // magic-mul div
    int k  = t0 - q0 * M41;
    int dq = q0 - q_lo;        // 0 <= dq <= 25 by construction

    unsigned int A[8], Bv[8];  // c=0: t0..t0+3 ; c=1: t0+1..t0+4
    #pragma unroll
    for (int j = 0; j < 5; ++j) {
        float  t1v = sT1[k];
        float2 t2v = sT2[k];
        if (j < 4) {
            uint2 f = feat(sE1[dq][0], t1v, t2v);
            A[2*j] = f.x; A[2*j + 1] = f.y;
        }
        if (j > 0) {
            uint2 f = feat(sE1[dq][1], t1v, t2v);
            Bv[2*(j-1)] = f.x; Bv[2*j - 1] = f.y;
        }
        if (++k == M41) { k = 0; ++dq; }
    }

    uint4 v;
    size_t i0 = base0 + 2 * (size_t)t0;          // 16B-aligned (t0 % 4 == 0)
    v.x = A[0]; v.y = A[1]; v.z = A[2]; v.w = A[3];
    *(uint4*)&out[i0] = v;
    v.x = A[4]; v.y = A[5]; v.z = A[6]; v.w = A[7];
    *(uint4*)&out[i0 + 4] = v;

    size_t i1 = base1 + 2 * (size_t)t0 + 2;      // 16B-aligned (plane base ≡ 2 mod 4)
    v.x = Bv[0]; v.y = Bv[1]; v.z = Bv[2]; v.w = Bv[3];
    *(uint4*)&out[i1] = v;
    v.x = Bv[4]; v.y = Bv[5]; v.z = Bv[6]; v.w = Bv[7];
    *(uint4*)&out[i1 + 4] = v;
}

extern "C" void kernel_launch(void* const* d_in, const int* in_sizes, int n_in,
                              void* d_out, int out_size, void* d_ws, size_t ws_size,
                              hipStream_t stream) {
    // Verified R6: inputs arrive with d_in[0] = E_imag, d_in[1] = E_real.
    const float* E_imag = (const float*)d_in[0];
    const float* E_real = (const float*)d_in[1];
    unsigned int* out = (unsigned int*)d_out;

    int B = in_sizes[0] / (2 * M41);   // 128 for the bench shapes

    dim3 grid((P_PER_B + 255) / 256, B);   // 51 x B
    so_features<<<grid, 256, 0, stream>>>(E_real, E_imag, out);
}